// Round 6
// baseline (364.040 us; speedup 1.0000x reference)
//
#include <hip/hip_runtime.h>
#include <hip/hip_bf16.h>

#define BB 1024
#define DD 256
#define KK 8
#define NCLS_ 71
#define BANK_ 32
#define BKROWS (BB*KK)        // 8192
#define NBROWS (NCLS_*BANK_)  // 2272

typedef __bf16 bf16x8 __attribute__((ext_vector_type(8)));
typedef __bf16 bf16x4 __attribute__((ext_vector_type(4)));
typedef float f32x4 __attribute__((ext_vector_type(4)));

// sigmoid-form gelu: ~5 VALU ops; abs err ~0.02 (threshold 6.96, bf16 chain
// already gives absmax ~2.0)
__device__ __forceinline__ float gelu_fast(float x) {
    float z = __expf(-1.702f * x);
    return x * __builtin_amdgcn_rcpf(1.0f + z);
}
// tanh via hw exp + raw rcp: ~5 VALU ops
__device__ __forceinline__ float tanh_fast(float y) {
    float z = __expf(2.0f * y);
    return 1.0f - 2.0f * __builtin_amdgcn_rcpf(z + 1.0f);
}
// LDS tiles are [rows][256] bf16 (512B row stride). XOR-swizzle byte offset to
// spread rows across banks for ds_read_b128 (T2, guide §6 G4).
__device__ __forceinline__ int swz(int row, int colByte) {
    return (row * 512 + colByte) ^ ((row & 7) << 4);
}

// C = A(LDS tile, bf16, swizzled) @ W^T (global bf16 [256,256] row-major).
// Wave computes rows [m_base, m_base+16*MT), cols [n_base, n_base+16*NT).
// mfma_f32_16x16x32_bf16: A lane l holds A[l&15, (l>>4)*8 + j];
// B lane l holds B[(l>>4)*8+j, l&15] = W[l&15, (l>>4)*8+j] (contiguous 16B).
template<int MT, int NT>
__device__ __forceinline__ void gemm_tile(const __bf16* __restrict__ Wg,
                                          const char* Ab, int m_base, int n_base,
                                          int lane, f32x4 (&acc)[MT][NT])
{
    #pragma unroll
    for (int ks = 0; ks < 8; ++ks) {
        bf16x8 a[MT];
        #pragma unroll
        for (int mt = 0; mt < MT; ++mt) {
            int row = m_base + mt*16 + (lane & 15);
            int cb  = ks*64 + ((lane >> 4) << 4);
            a[mt] = *reinterpret_cast<const bf16x8*>(Ab + swz(row, cb));
        }
        #pragma unroll
        for (int nt = 0; nt < NT; ++nt) {
            int n  = n_base + nt*16 + (lane & 15);
            int k0 = ks*32 + ((lane >> 4) << 3);
            bf16x8 b = *reinterpret_cast<const bf16x8*>(Wg + n*DD + k0);
            #pragma unroll
            for (int mt = 0; mt < MT; ++mt)
                acc[mt][nt] = __builtin_amdgcn_mfma_f32_16x16x32_bf16(a[mt], b, acc[mt][nt], 0, 0, 0);
        }
    }
}

// Fused prep: 6 weight casts (blocks 0..383), fea_bank cast (384..951),
// class means (952..1022).
__global__ __launch_bounds__(256) void k_prep(
    const float* __restrict__ We1f, const float* __restrict__ Wo1f,
    const float* __restrict__ We2f, const float* __restrict__ Wo2f,
    const float* __restrict__ Wf1f, const float* __restrict__ Wf2f,
    const float* __restrict__ fb,
    __bf16* __restrict__ We1, __bf16* __restrict__ Wo1,
    __bf16* __restrict__ We2, __bf16* __restrict__ Wo2,
    __bf16* __restrict__ Wf1, __bf16* __restrict__ Wf2,
    __bf16* __restrict__ fbb, float* __restrict__ fmean)
{
    int b = blockIdx.x, tid = threadIdx.x;
    if (b < 384) {
        int w = b >> 6;
        const float* s; __bf16* d;
        switch (w) {
            case 0: s = We1f; d = We1; break;
            case 1: s = Wo1f; d = Wo1; break;
            case 2: s = We2f; d = We2; break;
            case 3: s = Wo2f; d = Wo2; break;
            case 4: s = Wf1f; d = Wf1; break;
            default: s = Wf2f; d = Wf2; break;
        }
        int i = (b & 63)*256 + tid;
        float4 v = reinterpret_cast<const float4*>(s)[i];
        bf16x4 o = {(__bf16)v.x, (__bf16)v.y, (__bf16)v.z, (__bf16)v.w};
        *reinterpret_cast<bf16x4*>(d + i*4) = o;
    } else if (b < 952) {
        int i = (b - 384)*256 + tid;   // 568*256 = NBROWS*DD/4
        float4 v = reinterpret_cast<const float4*>(fb)[i];
        bf16x4 o = {(__bf16)v.x, (__bf16)v.y, (__bf16)v.z, (__bf16)v.w};
        *reinterpret_cast<bf16x4*>(fbb + i*4) = o;
    } else {
        int c = b - 952, d = tid;
        float s = 0.f;
        #pragma unroll
        for (int j = 0; j < BANK_; ++j) s += fb[(c*BANK_ + j)*DD + d];
        fmean[c*DD + d] = s * (1.0f / BANK_);
    }
}

// Stage 1 with inlined top-k: 1 target per block, 128 threads = 2 waves.
// Distances in fp32, exact reference tie-break (asc dist, lowest index).
__global__ __launch_bounds__(128) void k_stage1(
    const float* __restrict__ tgt, const float* __restrict__ fmean,
    int* __restrict__ idxg,
    const __bf16* __restrict__ We1, const float* __restrict__ be1,
    const __bf16* __restrict__ Wf1,
    const __bf16* __restrict__ Wo1, const float* __restrict__ bo1,
    float* __restrict__ out_s1, __bf16* __restrict__ s1b)
{
    __shared__ __bf16 As[16*256]; // 8KB swizzled tile
    __shared__ float tl[256];
    __shared__ float d2s[NCLS_ + 1];
    __shared__ int cls[8];
    char* Ab = (char*)As;
    int tid = threadIdx.x, lane = tid & 63, wid = tid >> 6;
    int b = blockIdx.x;
    if (tid < 64) reinterpret_cast<float4*>(tl)[tid] = reinterpret_cast<const float4*>(tgt + b*DD)[tid];
    // zero pad rows 8..15 of the MFMA tile
    {
        uint4 zz = {0u,0u,0u,0u};
        #pragma unroll
        for (int i = 0; i < 2; ++i) {
            int f = i*128 + tid;
            int row = 8 + (f >> 5), c = f & 31;
            *reinterpret_cast<uint4*>(Ab + swz(row, c*16)) = zz;
        }
    }
    __syncthreads();
    // distances to all 71 class means (wave0: 0..35, wave1: 36..70)
    {
        float t0 = tl[lane], t1 = tl[64+lane], t2 = tl[128+lane], t3 = tl[192+lane];
        int cbeg = wid*36, cend = cbeg + 36 - wid; // 0..35 / 36..70
        for (int c = cbeg; c < cend; ++c) {
            const float* m = fmean + c*DD;
            float a0 = t0 - m[lane], a1 = t1 - m[64+lane];
            float a2 = t2 - m[128+lane], a3 = t3 - m[192+lane];
            float p = a0*a0 + a1*a1 + a2*a2 + a3*a3;
            #pragma unroll
            for (int o = 32; o > 0; o >>= 1) p += __shfl_xor(p, o);
            if (lane == 0) d2s[c] = p;
        }
    }
    __syncthreads();
    // wave-parallel top-8: lexicographic (dist, idx) argmin butterfly x8
    if (wid == 0) {
        float d0 = d2s[lane];
        float d1 = (lane < NCLS_ - 64) ? d2s[64 + lane] : 3.4e38f;
        #pragma unroll
        for (int t = 0; t < KK; ++t) {
            float bd; int bi;
            if (d0 <= d1) { bd = d0; bi = lane; } else { bd = d1; bi = 64 + lane; }
            #pragma unroll
            for (int o = 1; o < 64; o <<= 1) {
                float od = __shfl_xor(bd, o);
                int   oi = __shfl_xor(bi, o);
                if (od < bd || (od == bd && oi < bi)) { bd = od; bi = oi; }
            }
            if (lane == 0) { cls[t] = bi; idxg[b*KK + t] = bi; }
            if (bi == lane)      d0 = 3.4e38f;
            if (bi == 64 + lane) d1 = 3.4e38f;
        }
    }
    __syncthreads();
    // X1[row,col] = fmean[cls[row],col] - t[col], rows 0..7
    int c16 = tid & 31, q = tid >> 5; // q in 0..3
    #pragma unroll
    for (int i = 0; i < 2; ++i) {
        int row = i*4 + q;
        const float* mb = fmean + cls[row]*DD + c16*8;
        const float* tb = tl + c16*8;
        float4 m0 = *(const float4*)mb, m1 = *(const float4*)(mb+4);
        float4 t0 = *(const float4*)tb, t1 = *(const float4*)(tb+4);
        bf16x8 o = {(__bf16)(m0.x-t0.x), (__bf16)(m0.y-t0.y), (__bf16)(m0.z-t0.z), (__bf16)(m0.w-t0.w),
                    (__bf16)(m1.x-t1.x), (__bf16)(m1.y-t1.y), (__bf16)(m1.z-t1.z), (__bf16)(m1.w-t1.w)};
        *reinterpret_cast<bf16x8*>(Ab + swz(row, c16*16)) = o;
    }
    __syncthreads();
    int n_base = wid * 128;       // NT=8: this wave's 128 cols
    int qr = lane >> 4;
    const f32x4 z = {0.f, 0.f, 0.f, 0.f};
    f32x4 acc[1][8];
    #pragma unroll
    for (int nt = 0; nt < 8; ++nt) acc[0][nt] = z;
    gemm_tile<1,8>(We1, Ab, 0, n_base, lane, acc);
    float e1reg[8][4];
    #pragma unroll
    for (int nt = 0; nt < 8; ++nt)
        #pragma unroll
        for (int r = 0; r < 4; ++r) {
            int col = n_base + nt*16 + (lane & 15);
            e1reg[nt][r] = gelu_fast(acc[0][nt][r] + be1[col]);
        }
    __syncthreads();
    if (qr < 2)
        #pragma unroll
        for (int nt = 0; nt < 8; ++nt)
            #pragma unroll
            for (int r = 0; r < 4; ++r) {
                int row = qr*4 + r;
                int col = n_base + nt*16 + (lane & 15);
                *(__bf16*)(Ab + swz(row, col*2)) = (__bf16)e1reg[nt][r];
            }
    __syncthreads();
    // GEMM2: w1 = E1 @ Wf1^T; softmax over the target's 8 rows (K axis)
    f32x4 acc2[1][8];
    #pragma unroll
    for (int nt = 0; nt < 8; ++nt) acc2[0][nt] = z;
    gemm_tile<1,8>(Wf1, Ab, 0, n_base, lane, acc2);
    float a2v[8][4];
    #pragma unroll
    for (int nt = 0; nt < 8; ++nt) {
        float mx = fmaxf(fmaxf(acc2[0][nt][0], acc2[0][nt][1]),
                         fmaxf(acc2[0][nt][2], acc2[0][nt][3]));
        mx = fmaxf(mx, __shfl_xor(mx, 16));
        float p[4], s = 0.f;
        #pragma unroll
        for (int r = 0; r < 4; ++r) { p[r] = __expf(acc2[0][nt][r] - mx); s += p[r]; }
        s += __shfl_xor(s, 16);
        float inv = __builtin_amdgcn_rcpf(s);
        int col = n_base + nt*16 + (lane & 15);
        #pragma unroll
        for (int r = 0; r < 4; ++r)
            a2v[nt][r] = tl[col] + e1reg[nt][r] * p[r] * inv;
    }
    __syncthreads();
    if (qr < 2)
        #pragma unroll
        for (int nt = 0; nt < 8; ++nt)
            #pragma unroll
            for (int r = 0; r < 4; ++r) {
                int row = qr*4 + r;
                int col = n_base + nt*16 + (lane & 15);
                *(__bf16*)(Ab + swz(row, col*2)) = (__bf16)a2v[nt][r];
            }
    __syncthreads();
    // GEMM3: off1 = tanh(A2 @ Wo1^T + bo1); s1 = (1+off1)*t
    #pragma unroll
    for (int nt = 0; nt < 8; ++nt) acc[0][nt] = z;
    gemm_tile<1,8>(Wo1, Ab, 0, n_base, lane, acc);
    if (qr < 2)
        #pragma unroll
        for (int nt = 0; nt < 8; ++nt)
            #pragma unroll
            for (int r = 0; r < 4; ++r) {
                int row = qr*4 + r;
                int col = n_base + nt*16 + (lane & 15);
                float off = tanh_fast(acc[0][nt][r] + bo1[col]);
                float s1v = (1.0f + off) * tl[col];
                int g = (b*8 + row)*DD + col;
                out_s1[g] = s1v;
                s1b[g] = (__bf16)s1v;
            }
}

// Merged GEMMs, 32-row blocks, bf16 outputs.
// blocks 0..70: FBe2b = fbb@We2^T + be2; blocks 71..326: dual on s1b.
__global__ __launch_bounds__(256) void k_gemms(
    const __bf16* __restrict__ fbb, const __bf16* __restrict__ s1b,
    const __bf16* __restrict__ We2, const __bf16* __restrict__ Wo2,
    const float* __restrict__ be2, const float* __restrict__ bo2,
    __bf16* __restrict__ FBe2b, __bf16* __restrict__ S1We2, __bf16* __restrict__ S1Wo2)
{
    __shared__ __bf16 As[32*256]; // 16KB
    char* Ab = (char*)As;
    int tid = threadIdx.x, lane = tid & 63, wid = tid >> 6;
    bool fbpath = blockIdx.x < 71;
    const __bf16* A = fbpath ? fbb : s1b;
    int m0 = fbpath ? blockIdx.x * 32 : (blockIdx.x - 71) * 32;
    #pragma unroll
    for (int i = 0; i < 4; ++i) {
        int f = i*256 + tid;
        int row = f >> 5, c16 = f & 31;
        uint4 v = *reinterpret_cast<const uint4*>(A + (size_t)(m0+row)*DD + c16*8);
        *reinterpret_cast<uint4*>(Ab + swz(row, c16*16)) = v;
    }
    __syncthreads();
    int n_base = wid * 64;  // 4 waves x 64 cols, MT=2 covers all 32 rows
    const f32x4 z = {0.f, 0.f, 0.f, 0.f};
    f32x4 acc[2][4];
    #pragma unroll
    for (int mt = 0; mt < 2; ++mt)
        #pragma unroll
        for (int nt = 0; nt < 4; ++nt) acc[mt][nt] = z;
    gemm_tile<2,4>(We2, Ab, 0, n_base, lane, acc);
    #pragma unroll
    for (int mt = 0; mt < 2; ++mt)
        #pragma unroll
        for (int nt = 0; nt < 4; ++nt)
            #pragma unroll
            for (int r = 0; r < 4; ++r) {
                int row = mt*16 + ((lane >> 4) << 2) + r;
                int col = n_base + nt*16 + (lane & 15);
                if (fbpath) FBe2b[(size_t)(m0+row)*DD + col] = (__bf16)(acc[mt][nt][r] + be2[col]);
                else        S1We2[(size_t)(m0+row)*DD + col] = (__bf16)acc[mt][nt][r];
            }
    if (!fbpath) {
        #pragma unroll
        for (int mt = 0; mt < 2; ++mt)
            #pragma unroll
            for (int nt = 0; nt < 4; ++nt) acc[mt][nt] = z;
        gemm_tile<2,4>(Wo2, Ab, 0, n_base, lane, acc);
        #pragma unroll
        for (int mt = 0; mt < 2; ++mt)
            #pragma unroll
            for (int nt = 0; nt < 4; ++nt)
                #pragma unroll
                for (int r = 0; r < 4; ++r) {
                    int row = mt*16 + ((lane >> 4) << 2) + r;
                    int col = n_base + nt*16 + (lane & 15);
                    S1Wo2[(size_t)(m0+row)*DD + col] = (__bf16)(acc[mt][nt][r] + bo2[col]);
                }
    }
}

// Stage 2 fused: block = 4 units (128 rows), 1024 threads, 16 waves.
// Wave (h = wid>>3, n = wid&7): rows h*64..h*64+63 (MT=4), cols n*32 (NT=2).
// acc = 32 floats -> no spill at 64-VGPR budget; 64KB LDS -> 2 blocks/CU.
__global__ __launch_bounds__(1024, 8) void k_stage2(
    const int* __restrict__ idx,
    const __bf16* __restrict__ FBe2b,   // fea_bank@We2^T + be2  [2272,256] bf16
    const __bf16* __restrict__ S1We2,   // s1@We2^T              [8192,256] bf16
    const __bf16* __restrict__ S1Wo2,   // s1@Wo2^T + bo2        [8192,256] bf16
    const __bf16* __restrict__ Wf2,
    const __bf16* __restrict__ Wo2,
    const float* __restrict__ s1,       // d_out first half
    float* __restrict__ s2)             // d_out second half
{
    __shared__ __bf16 As[128*256]; // 64KB swizzled E2 tile
    __shared__ int clss[4];
    char* Ab = (char*)As;
    int tid = threadIdx.x, lane = tid & 63, wid = tid >> 6;
    int u0 = blockIdx.x * 4;
    if (tid < 4) clss[tid] = idx[u0 + tid];
    __syncthreads();
    // Build E2 = gelu(FBe2b[class*32+j] - S1We2[u]) into LDS (bf16).
    // Bijective: c16 = tid&31, q = tid>>5 (0..31); 4 iters x 32 rows.
    int c16 = tid & 31, q = tid >> 5;
    #pragma unroll
    for (int i = 0; i < 4; ++i) {
        int row = i*32 + q;
        int unit = row >> 5, j = row & 31;
        bf16x8 f = *reinterpret_cast<const bf16x8*>(FBe2b + ((size_t)clss[unit]*BANK_ + j)*DD + c16*8);
        bf16x8 g = *reinterpret_cast<const bf16x8*>(S1We2 + (size_t)(u0+unit)*DD + c16*8);
        bf16x8 o;
        #pragma unroll
        for (int e = 0; e < 8; ++e) o[e] = (__bf16)gelu_fast((float)f[e] - (float)g[e]);
        *reinterpret_cast<bf16x8*>(Ab + swz(row, c16*16)) = o;
    }
    __syncthreads();
    int h = wid >> 3;             // row half (2 units each)
    int m_base = h * 64;
    int n_base = (wid & 7) * 32;
    const f32x4 z = {0.f, 0.f, 0.f, 0.f};
    f32x4 acc[4][2];
    #pragma unroll
    for (int mt = 0; mt < 4; ++mt)
        #pragma unroll
        for (int nt = 0; nt < 2; ++nt) acc[mt][nt] = z;
    gemm_tile<4,2>(Wf2, Ab, m_base, n_base, lane, acc);
    // softmax over the 32 BANK rows of each unit, per column; acc <- exp
    float inv_[2][2];
    #pragma unroll
    for (int uiw = 0; uiw < 2; ++uiw)
        #pragma unroll
        for (int nt = 0; nt < 2; ++nt) {
            float mx = -3.4e38f;
            #pragma unroll
            for (int mh = 0; mh < 2; ++mh)
                #pragma unroll
                for (int r = 0; r < 4; ++r) mx = fmaxf(mx, acc[uiw*2+mh][nt][r]);
            mx = fmaxf(mx, __shfl_xor(mx, 16));
            mx = fmaxf(mx, __shfl_xor(mx, 32));
            float s = 0.f;
            #pragma unroll
            for (int mh = 0; mh < 2; ++mh)
                #pragma unroll
                for (int r = 0; r < 4; ++r) {
                    float e = __expf(acc[uiw*2+mh][nt][r] - mx);
                    acc[uiw*2+mh][nt][r] = e;
                    s += e;
                }
            s += __shfl_xor(s, 16);
            s += __shfl_xor(s, 32);
            inv_[uiw][nt] = __builtin_amdgcn_rcpf(s);
        }
    __syncthreads(); // all GEMM1 reads of As done
    // E2' = E2 * softmax (each wave owns rows m_base..+63 x its 32-col slab)
    #pragma unroll
    for (int mt = 0; mt < 4; ++mt)
        #pragma unroll
        for (int nt = 0; nt < 2; ++nt)
            #pragma unroll
            for (int r = 0; r < 4; ++r) {
                int row = m_base + mt*16 + ((lane >> 4) << 2) + r;
                int col = n_base + nt*16 + (lane & 15);
                __bf16* p16 = (__bf16*)(Ab + swz(row, col*2));
                *p16 = (__bf16)((float)*p16 * acc[mt][nt][r] * inv_[mt>>1][nt]);
            }
    __syncthreads();
    // GEMM2: E2' @ Wo2^T, then tanh + per-unit column-sum epilogue
    #pragma unroll
    for (int mt = 0; mt < 4; ++mt)
        #pragma unroll
        for (int nt = 0; nt < 2; ++nt) acc[mt][nt] = z;
    gemm_tile<4,2>(Wo2, Ab, m_base, n_base, lane, acc);
    #pragma unroll
    for (int uiw = 0; uiw < 2; ++uiw) {
        size_t u = u0 + 2*h + uiw;
        #pragma unroll
        for (int nt = 0; nt < 2; ++nt) {
            int col = n_base + nt*16 + (lane & 15);
            float srow = (float)S1Wo2[u*DD + col];
            float cs = 0.f;
            #pragma unroll
            for (int mh = 0; mh < 2; ++mh)
                #pragma unroll
                for (int r = 0; r < 4; ++r) cs += tanh_fast(acc[uiw*2+mh][nt][r] + srow);
            cs += __shfl_xor(cs, 16);
            cs += __shfl_xor(cs, 32);
            if ((lane >> 4) == 0)
                s2[u*DD + col] = s1[u*DD + col] * (32.0f + cs);
        }
    }
}

extern "C" void kernel_launch(void* const* d_in, const int* in_sizes, int n_in,
                              void* d_out, int out_size, void* d_ws, size_t ws_size,
                              hipStream_t stream)
{
    const float* tgt  = (const float*)d_in[0];
    const float* fb   = (const float*)d_in[1];
    const float* We1f = (const float*)d_in[2];
    const float* be1  = (const float*)d_in[3];
    const float* Wo1f = (const float*)d_in[4];
    const float* bo1  = (const float*)d_in[5];
    const float* We2f = (const float*)d_in[6];
    const float* be2  = (const float*)d_in[7];
    const float* Wo2f = (const float*)d_in[8];
    const float* bo2  = (const float*)d_in[9];
    const float* Wf1f = (const float*)d_in[10];
    const float* Wf2f = (const float*)d_in[11];

    char* ws = (char*)d_ws;
    size_t off = 0;
    auto alloc = [&](size_t bytes) { char* p = ws + off; off += (bytes + 255) & ~255ull; return p; };
    float*  fmean = (float*)alloc(NCLS_*DD*4);
    int*    idx   = (int*)alloc(BB*KK*4);
    __bf16* We1   = (__bf16*)alloc(DD*DD*2);
    __bf16* Wo1   = (__bf16*)alloc(DD*DD*2);
    __bf16* We2   = (__bf16*)alloc(DD*DD*2);
    __bf16* Wo2   = (__bf16*)alloc(DD*DD*2);
    __bf16* Wf1   = (__bf16*)alloc(DD*DD*2);
    __bf16* Wf2   = (__bf16*)alloc(DD*DD*2);
    __bf16* fbb   = (__bf16*)alloc((size_t)NBROWS*DD*2);
    __bf16* s1b   = (__bf16*)alloc((size_t)BKROWS*DD*2);
    __bf16* FBe2b = (__bf16*)alloc((size_t)NBROWS*DD*2);
    __bf16* S1We2 = (__bf16*)alloc((size_t)BKROWS*DD*2);
    __bf16* S1Wo2 = (__bf16*)alloc((size_t)BKROWS*DD*2);

    float* out_s1 = (float*)d_out;
    float* out_s2 = out_s1 + (size_t)BKROWS*DD;

    k_prep<<<1023, 256, 0, stream>>>(We1f, Wo1f, We2f, Wo2f, Wf1f, Wf2f, fb,
                                     We1, Wo1, We2, Wo2, Wf1, Wf2, fbb, fmean);
    k_stage1<<<BB, 128, 0, stream>>>(tgt, fmean, idx, We1, be1, Wf1, Wo1, bo1, out_s1, s1b);
    k_gemms<<<71 + BKROWS/32, 256, 0, stream>>>(fbb, s1b, We2, Wo2, be2, bo2,
                                                FBe2b, S1We2, S1Wo2);
    k_stage2<<<BKROWS/4, 1024, 0, stream>>>(idx, FBe2b, S1We2, S1Wo2, Wf2, Wo2, out_s1, out_s2);
}

// Round 7
// 356.638 us; speedup vs baseline: 1.0208x; 1.0208x over previous
//
#include <hip/hip_runtime.h>
#include <hip/hip_bf16.h>

#define BB 1024
#define DD 256
#define KK 8
#define NCLS_ 71
#define BANK_ 32
#define BKROWS (BB*KK)        // 8192
#define NBROWS (NCLS_*BANK_)  // 2272

typedef __bf16 bf16x8 __attribute__((ext_vector_type(8)));
typedef __bf16 bf16x4 __attribute__((ext_vector_type(4)));
typedef float f32x4 __attribute__((ext_vector_type(4)));

// sigmoid-form gelu: ~5 VALU ops; abs err ~0.02 (threshold 6.96)
__device__ __forceinline__ float gelu_fast(float x) {
    float z = __expf(-1.702f * x);
    return x * __builtin_amdgcn_rcpf(1.0f + z);
}
// tanh via hw exp + raw rcp: ~5 VALU ops
__device__ __forceinline__ float tanh_fast(float y) {
    float z = __expf(2.0f * y);
    return 1.0f - 2.0f * __builtin_amdgcn_rcpf(z + 1.0f);
}
// LDS tiles are [rows][256] bf16 (512B row stride). XOR-swizzle byte offset to
// spread rows across banks for ds_read_b128 (T2, guide §6 G4).
__device__ __forceinline__ int swz(int row, int colByte) {
    return (row * 512 + colByte) ^ ((row & 7) << 4);
}

// C = A(LDS tile, bf16, swizzled) @ W^T (global bf16 [256,256] row-major).
template<int MT, int NT>
__device__ __forceinline__ void gemm_tile(const __bf16* __restrict__ Wg,
                                          const char* Ab, int m_base, int n_base,
                                          int lane, f32x4 (&acc)[MT][NT])
{
    #pragma unroll
    for (int ks = 0; ks < 8; ++ks) {
        bf16x8 a[MT];
        #pragma unroll
        for (int mt = 0; mt < MT; ++mt) {
            int row = m_base + mt*16 + (lane & 15);
            int cb  = ks*64 + ((lane >> 4) << 4);
            a[mt] = *reinterpret_cast<const bf16x8*>(Ab + swz(row, cb));
        }
        #pragma unroll
        for (int nt = 0; nt < NT; ++nt) {
            int n  = n_base + nt*16 + (lane & 15);
            int k0 = ks*32 + ((lane >> 4) << 3);
            bf16x8 b = *reinterpret_cast<const bf16x8*>(Wg + n*DD + k0);
            #pragma unroll
            for (int mt = 0; mt < MT; ++mt)
                acc[mt][nt] = __builtin_amdgcn_mfma_f32_16x16x32_bf16(a[mt], b, acc[mt][nt], 0, 0, 0);
        }
    }
}

// Fused prep: 6 weight casts (blocks 0..383), fea_bank cast (384..951),
// class means (952..1022).
__global__ __launch_bounds__(256) void k_prep(
    const float* __restrict__ We1f, const float* __restrict__ Wo1f,
    const float* __restrict__ We2f, const float* __restrict__ Wo2f,
    const float* __restrict__ Wf1f, const float* __restrict__ Wf2f,
    const float* __restrict__ fb,
    __bf16* __restrict__ We1, __bf16* __restrict__ Wo1,
    __bf16* __restrict__ We2, __bf16* __restrict__ Wo2,
    __bf16* __restrict__ Wf1, __bf16* __restrict__ Wf2,
    __bf16* __restrict__ fbb, float* __restrict__ fmean)
{
    int b = blockIdx.x, tid = threadIdx.x;
    if (b < 384) {
        int w = b >> 6;
        const float* s; __bf16* d;
        switch (w) {
            case 0: s = We1f; d = We1; break;
            case 1: s = Wo1f; d = Wo1; break;
            case 2: s = We2f; d = We2; break;
            case 3: s = Wo2f; d = Wo2; break;
            case 4: s = Wf1f; d = Wf1; break;
            default: s = Wf2f; d = Wf2; break;
        }
        int i = (b & 63)*256 + tid;
        float4 v = reinterpret_cast<const float4*>(s)[i];
        bf16x4 o = {(__bf16)v.x, (__bf16)v.y, (__bf16)v.z, (__bf16)v.w};
        *reinterpret_cast<bf16x4*>(d + i*4) = o;
    } else if (b < 952) {
        int i = (b - 384)*256 + tid;   // 568*256 = NBROWS*DD/4
        float4 v = reinterpret_cast<const float4*>(fb)[i];
        bf16x4 o = {(__bf16)v.x, (__bf16)v.y, (__bf16)v.z, (__bf16)v.w};
        *reinterpret_cast<bf16x4*>(fbb + i*4) = o;
    } else {
        int c = b - 952, d = tid;
        float s = 0.f;
        #pragma unroll
        for (int j = 0; j < BANK_; ++j) s += fb[(c*BANK_ + j)*DD + d];
        fmean[c*DD + d] = s * (1.0f / BANK_);
    }
}

// Stage 1 with inlined top-k: 1 target per block, 128 threads = 2 waves.
// Distances in fp32, exact reference tie-break (asc dist, lowest index).
__global__ __launch_bounds__(128) void k_stage1(
    const float* __restrict__ tgt, const float* __restrict__ fmean,
    int* __restrict__ idxg,
    const __bf16* __restrict__ We1, const float* __restrict__ be1,
    const __bf16* __restrict__ Wf1,
    const __bf16* __restrict__ Wo1, const float* __restrict__ bo1,
    float* __restrict__ out_s1, __bf16* __restrict__ s1b)
{
    __shared__ __bf16 As[16*256]; // 8KB swizzled tile
    __shared__ float tl[256];
    __shared__ float d2s[NCLS_ + 1];
    __shared__ int cls[8];
    char* Ab = (char*)As;
    int tid = threadIdx.x, lane = tid & 63, wid = tid >> 6;
    int b = blockIdx.x;
    if (tid < 64) reinterpret_cast<float4*>(tl)[tid] = reinterpret_cast<const float4*>(tgt + b*DD)[tid];
    // zero pad rows 8..15 of the MFMA tile
    {
        uint4 zz = {0u,0u,0u,0u};
        #pragma unroll
        for (int i = 0; i < 2; ++i) {
            int f = i*128 + tid;
            int row = 8 + (f >> 5), c = f & 31;
            *reinterpret_cast<uint4*>(Ab + swz(row, c*16)) = zz;
        }
    }
    __syncthreads();
    // distances to all 71 class means (wave0: 0..35, wave1: 36..70)
    {
        float t0 = tl[lane], t1 = tl[64+lane], t2 = tl[128+lane], t3 = tl[192+lane];
        int cbeg = wid*36, cend = cbeg + 36 - wid; // 0..35 / 36..70
        for (int c = cbeg; c < cend; ++c) {
            const float* m = fmean + c*DD;
            float a0 = t0 - m[lane], a1 = t1 - m[64+lane];
            float a2 = t2 - m[128+lane], a3 = t3 - m[192+lane];
            float p = a0*a0 + a1*a1 + a2*a2 + a3*a3;
            #pragma unroll
            for (int o = 32; o > 0; o >>= 1) p += __shfl_xor(p, o);
            if (lane == 0) d2s[c] = p;
        }
    }
    __syncthreads();
    // wave-parallel top-8: lexicographic (dist, idx) argmin butterfly x8
    if (wid == 0) {
        float d0 = d2s[lane];
        float d1 = (lane < NCLS_ - 64) ? d2s[64 + lane] : 3.4e38f;
        #pragma unroll
        for (int t = 0; t < KK; ++t) {
            float bd; int bi;
            if (d0 <= d1) { bd = d0; bi = lane; } else { bd = d1; bi = 64 + lane; }
            #pragma unroll
            for (int o = 1; o < 64; o <<= 1) {
                float od = __shfl_xor(bd, o);
                int   oi = __shfl_xor(bi, o);
                if (od < bd || (od == bd && oi < bi)) { bd = od; bi = oi; }
            }
            if (lane == 0) { cls[t] = bi; idxg[b*KK + t] = bi; }
            if (bi == lane)      d0 = 3.4e38f;
            if (bi == 64 + lane) d1 = 3.4e38f;
        }
    }
    __syncthreads();
    // X1[row,col] = fmean[cls[row],col] - t[col], rows 0..7
    int c16 = tid & 31, q = tid >> 5; // q in 0..3
    #pragma unroll
    for (int i = 0; i < 2; ++i) {
        int row = i*4 + q;
        const float* mb = fmean + cls[row]*DD + c16*8;
        const float* tb = tl + c16*8;
        float4 m0 = *(const float4*)mb, m1 = *(const float4*)(mb+4);
        float4 t0 = *(const float4*)tb, t1 = *(const float4*)(tb+4);
        bf16x8 o = {(__bf16)(m0.x-t0.x), (__bf16)(m0.y-t0.y), (__bf16)(m0.z-t0.z), (__bf16)(m0.w-t0.w),
                    (__bf16)(m1.x-t1.x), (__bf16)(m1.y-t1.y), (__bf16)(m1.z-t1.z), (__bf16)(m1.w-t1.w)};
        *reinterpret_cast<bf16x8*>(Ab + swz(row, c16*16)) = o;
    }
    __syncthreads();
    int n_base = wid * 128;       // NT=8: this wave's 128 cols
    int qr = lane >> 4;
    const f32x4 z = {0.f, 0.f, 0.f, 0.f};
    f32x4 acc[1][8];
    #pragma unroll
    for (int nt = 0; nt < 8; ++nt) acc[0][nt] = z;
    gemm_tile<1,8>(We1, Ab, 0, n_base, lane, acc);
    float e1reg[8][4];
    #pragma unroll
    for (int nt = 0; nt < 8; ++nt)
        #pragma unroll
        for (int r = 0; r < 4; ++r) {
            int col = n_base + nt*16 + (lane & 15);
            e1reg[nt][r] = gelu_fast(acc[0][nt][r] + be1[col]);
        }
    __syncthreads();
    if (qr < 2)
        #pragma unroll
        for (int nt = 0; nt < 8; ++nt)
            #pragma unroll
            for (int r = 0; r < 4; ++r) {
                int row = qr*4 + r;
                int col = n_base + nt*16 + (lane & 15);
                *(__bf16*)(Ab + swz(row, col*2)) = (__bf16)e1reg[nt][r];
            }
    __syncthreads();
    // GEMM2: w1 = E1 @ Wf1^T; softmax over the target's 8 rows (K axis)
    f32x4 acc2[1][8];
    #pragma unroll
    for (int nt = 0; nt < 8; ++nt) acc2[0][nt] = z;
    gemm_tile<1,8>(Wf1, Ab, 0, n_base, lane, acc2);
    float a2v[8][4];
    #pragma unroll
    for (int nt = 0; nt < 8; ++nt) {
        float mx = fmaxf(fmaxf(acc2[0][nt][0], acc2[0][nt][1]),
                         fmaxf(acc2[0][nt][2], acc2[0][nt][3]));
        mx = fmaxf(mx, __shfl_xor(mx, 16));
        float p[4], s = 0.f;
        #pragma unroll
        for (int r = 0; r < 4; ++r) { p[r] = __expf(acc2[0][nt][r] - mx); s += p[r]; }
        s += __shfl_xor(s, 16);
        float inv = __builtin_amdgcn_rcpf(s);
        int col = n_base + nt*16 + (lane & 15);
        #pragma unroll
        for (int r = 0; r < 4; ++r)
            a2v[nt][r] = tl[col] + e1reg[nt][r] * p[r] * inv;
    }
    __syncthreads();
    if (qr < 2)
        #pragma unroll
        for (int nt = 0; nt < 8; ++nt)
            #pragma unroll
            for (int r = 0; r < 4; ++r) {
                int row = qr*4 + r;
                int col = n_base + nt*16 + (lane & 15);
                *(__bf16*)(Ab + swz(row, col*2)) = (__bf16)a2v[nt][r];
            }
    __syncthreads();
    // GEMM3: off1 = tanh(A2 @ Wo1^T + bo1); s1 = (1+off1)*t
    #pragma unroll
    for (int nt = 0; nt < 8; ++nt) acc[0][nt] = z;
    gemm_tile<1,8>(Wo1, Ab, 0, n_base, lane, acc);
    if (qr < 2)
        #pragma unroll
        for (int nt = 0; nt < 8; ++nt)
            #pragma unroll
            for (int r = 0; r < 4; ++r) {
                int row = qr*4 + r;
                int col = n_base + nt*16 + (lane & 15);
                float off = tanh_fast(acc[0][nt][r] + bo1[col]);
                float s1v = (1.0f + off) * tl[col];
                int g = (b*8 + row)*DD + col;
                out_s1[g] = s1v;
                s1b[g] = (__bf16)s1v;
            }
}

// Merged GEMMs, 32-row blocks, bf16 outputs.
// blocks 0..70: FBe2b = fbb@We2^T + be2; blocks 71..326: dual on s1b.
__global__ __launch_bounds__(256) void k_gemms(
    const __bf16* __restrict__ fbb, const __bf16* __restrict__ s1b,
    const __bf16* __restrict__ We2, const __bf16* __restrict__ Wo2,
    const float* __restrict__ be2, const float* __restrict__ bo2,
    __bf16* __restrict__ FBe2b, __bf16* __restrict__ S1We2, __bf16* __restrict__ S1Wo2)
{
    __shared__ __bf16 As[32*256]; // 16KB
    char* Ab = (char*)As;
    int tid = threadIdx.x, lane = tid & 63, wid = tid >> 6;
    bool fbpath = blockIdx.x < 71;
    const __bf16* A = fbpath ? fbb : s1b;
    int m0 = fbpath ? blockIdx.x * 32 : (blockIdx.x - 71) * 32;
    #pragma unroll
    for (int i = 0; i < 4; ++i) {
        int f = i*256 + tid;
        int row = f >> 5, c16 = f & 31;
        uint4 v = *reinterpret_cast<const uint4*>(A + (size_t)(m0+row)*DD + c16*8);
        *reinterpret_cast<uint4*>(Ab + swz(row, c16*16)) = v;
    }
    __syncthreads();
    int n_base = wid * 64;  // 4 waves x 64 cols, MT=2 covers all 32 rows
    const f32x4 z = {0.f, 0.f, 0.f, 0.f};
    f32x4 acc[2][4];
    #pragma unroll
    for (int mt = 0; mt < 2; ++mt)
        #pragma unroll
        for (int nt = 0; nt < 4; ++nt) acc[mt][nt] = z;
    gemm_tile<2,4>(We2, Ab, 0, n_base, lane, acc);
    #pragma unroll
    for (int mt = 0; mt < 2; ++mt)
        #pragma unroll
        for (int nt = 0; nt < 4; ++nt)
            #pragma unroll
            for (int r = 0; r < 4; ++r) {
                int row = mt*16 + ((lane >> 4) << 2) + r;
                int col = n_base + nt*16 + (lane & 15);
                if (fbpath) FBe2b[(size_t)(m0+row)*DD + col] = (__bf16)(acc[mt][nt][r] + be2[col]);
                else        S1We2[(size_t)(m0+row)*DD + col] = (__bf16)acc[mt][nt][r];
            }
    if (!fbpath) {
        #pragma unroll
        for (int mt = 0; mt < 2; ++mt)
            #pragma unroll
            for (int nt = 0; nt < 4; ++nt) acc[mt][nt] = z;
        gemm_tile<2,4>(Wo2, Ab, 0, n_base, lane, acc);
        #pragma unroll
        for (int mt = 0; mt < 2; ++mt)
            #pragma unroll
            for (int nt = 0; nt < 4; ++nt)
                #pragma unroll
                for (int r = 0; r < 4; ++r) {
                    int row = mt*16 + ((lane >> 4) << 2) + r;
                    int col = n_base + nt*16 + (lane & 15);
                    S1Wo2[(size_t)(m0+row)*DD + col] = (__bf16)(acc[mt][nt][r] + bo2[col]);
                }
    }
}

// Stage 2 fused: block = 1 unit (32 rows), 256 threads, 4 waves.
// Wave: all 32 rows (MT=2) x 64 cols (NT=4); acc = 32 floats (proven no-spill
// shape, VGPR ~60-90 at 128 budget). Small blocks pack 4+/CU so phases of
// different blocks interleave (hide E2-build latency + barrier drains).
__global__ __launch_bounds__(256, 4) void k_stage2(
    const int* __restrict__ idx,
    const __bf16* __restrict__ FBe2b,   // fea_bank@We2^T + be2  [2272,256] bf16
    const __bf16* __restrict__ S1We2,   // s1@We2^T              [8192,256] bf16
    const __bf16* __restrict__ S1Wo2,   // s1@Wo2^T + bo2        [8192,256] bf16
    const __bf16* __restrict__ Wf2,
    const __bf16* __restrict__ Wo2,
    const float* __restrict__ s1,       // d_out first half
    float* __restrict__ s2)             // d_out second half
{
    __shared__ __bf16 As[32*256]; // 16KB swizzled E2 tile
    char* Ab = (char*)As;
    int tid = threadIdx.x, lane = tid & 63, wid = tid >> 6;
    size_t u = blockIdx.x;
    int cls = idx[u];
    // Build E2 = gelu(FBe2b[cls*32+j] - S1We2[u]) into LDS (bf16).
    // Bijective: c16 = tid&31 (bits 0-4), q = tid>>5 (bits 5-7, 0..7); 4 iters.
    int c16 = tid & 31, q = tid >> 5;
    #pragma unroll
    for (int i = 0; i < 4; ++i) {
        int row = i*8 + q;
        bf16x8 f = *reinterpret_cast<const bf16x8*>(FBe2b + ((size_t)cls*BANK_ + row)*DD + c16*8);
        bf16x8 g = *reinterpret_cast<const bf16x8*>(S1We2 + u*DD + c16*8);
        bf16x8 o;
        #pragma unroll
        for (int e = 0; e < 8; ++e) o[e] = (__bf16)gelu_fast((float)f[e] - (float)g[e]);
        *reinterpret_cast<bf16x8*>(Ab + swz(row, c16*16)) = o;
    }
    __syncthreads();
    int n_base = wid * 64;
    const f32x4 z = {0.f, 0.f, 0.f, 0.f};
    f32x4 acc[2][4];
    #pragma unroll
    for (int mt = 0; mt < 2; ++mt)
        #pragma unroll
        for (int nt = 0; nt < 4; ++nt) acc[mt][nt] = z;
    gemm_tile<2,4>(Wf2, Ab, 0, n_base, lane, acc);
    // softmax over the 32 BANK rows, per column; acc <- exp
    float inv_[4];
    #pragma unroll
    for (int nt = 0; nt < 4; ++nt) {
        float mx = -3.4e38f;
        #pragma unroll
        for (int mt = 0; mt < 2; ++mt)
            #pragma unroll
            for (int r = 0; r < 4; ++r) mx = fmaxf(mx, acc[mt][nt][r]);
        mx = fmaxf(mx, __shfl_xor(mx, 16));
        mx = fmaxf(mx, __shfl_xor(mx, 32));
        float s = 0.f;
        #pragma unroll
        for (int mt = 0; mt < 2; ++mt)
            #pragma unroll
            for (int r = 0; r < 4; ++r) {
                float e = __expf(acc[mt][nt][r] - mx);
                acc[mt][nt][r] = e;
                s += e;
            }
        s += __shfl_xor(s, 16);
        s += __shfl_xor(s, 32);
        inv_[nt] = __builtin_amdgcn_rcpf(s);
    }
    __syncthreads(); // all GEMM1 reads of As done
    // E2' = E2 * softmax (each wave owns its 64-col slab -> race-free)
    #pragma unroll
    for (int mt = 0; mt < 2; ++mt)
        #pragma unroll
        for (int nt = 0; nt < 4; ++nt)
            #pragma unroll
            for (int r = 0; r < 4; ++r) {
                int row = mt*16 + ((lane >> 4) << 2) + r;
                int col = n_base + nt*16 + (lane & 15);
                __bf16* p16 = (__bf16*)(Ab + swz(row, col*2));
                *p16 = (__bf16)((float)*p16 * acc[mt][nt][r] * inv_[nt]);
            }
    __syncthreads();
    // GEMM2: E2' @ Wo2^T, then tanh + column-sum epilogue
    #pragma unroll
    for (int mt = 0; mt < 2; ++mt)
        #pragma unroll
        for (int nt = 0; nt < 4; ++nt) acc[mt][nt] = z;
    gemm_tile<2,4>(Wo2, Ab, 0, n_base, lane, acc);
    #pragma unroll
    for (int nt = 0; nt < 4; ++nt) {
        int col = n_base + nt*16 + (lane & 15);
        float srow = (float)S1Wo2[u*DD + col];
        float cs = 0.f;
        #pragma unroll
        for (int mt = 0; mt < 2; ++mt)
            #pragma unroll
            for (int r = 0; r < 4; ++r) cs += tanh_fast(acc[mt][nt][r] + srow);
        cs += __shfl_xor(cs, 16);
        cs += __shfl_xor(cs, 32);
        if ((lane >> 4) == 0)
            s2[u*DD + col] = s1[u*DD + col] * (32.0f + cs);
    }
}

extern "C" void kernel_launch(void* const* d_in, const int* in_sizes, int n_in,
                              void* d_out, int out_size, void* d_ws, size_t ws_size,
                              hipStream_t stream)
{
    const float* tgt  = (const float*)d_in[0];
    const float* fb   = (const float*)d_in[1];
    const float* We1f = (const float*)d_in[2];
    const float* be1  = (const float*)d_in[3];
    const float* Wo1f = (const float*)d_in[4];
    const float* bo1  = (const float*)d_in[5];
    const float* We2f = (const float*)d_in[6];
    const float* be2  = (const float*)d_in[7];
    const float* Wo2f = (const float*)d_in[8];
    const float* bo2  = (const float*)d_in[9];
    const float* Wf1f = (const float*)d_in[10];
    const float* Wf2f = (const float*)d_in[11];

    char* ws = (char*)d_ws;
    size_t off = 0;
    auto alloc = [&](size_t bytes) { char* p = ws + off; off += (bytes + 255) & ~255ull; return p; };
    float*  fmean = (float*)alloc(NCLS_*DD*4);
    int*    idx   = (int*)alloc(BB*KK*4);
    __bf16* We1   = (__bf16*)alloc(DD*DD*2);
    __bf16* Wo1   = (__bf16*)alloc(DD*DD*2);
    __bf16* We2   = (__bf16*)alloc(DD*DD*2);
    __bf16* Wo2   = (__bf16*)alloc(DD*DD*2);
    __bf16* Wf1   = (__bf16*)alloc(DD*DD*2);
    __bf16* Wf2   = (__bf16*)alloc(DD*DD*2);
    __bf16* fbb   = (__bf16*)alloc((size_t)NBROWS*DD*2);
    __bf16* s1b   = (__bf16*)alloc((size_t)BKROWS*DD*2);
    __bf16* FBe2b = (__bf16*)alloc((size_t)NBROWS*DD*2);
    __bf16* S1We2 = (__bf16*)alloc((size_t)BKROWS*DD*2);
    __bf16* S1Wo2 = (__bf16*)alloc((size_t)BKROWS*DD*2);

    float* out_s1 = (float*)d_out;
    float* out_s2 = out_s1 + (size_t)BKROWS*DD;

    k_prep<<<1023, 256, 0, stream>>>(We1f, Wo1f, We2f, Wo2f, Wf1f, Wf2f, fb,
                                     We1, Wo1, We2, Wo2, Wf1, Wf2, fbb, fmean);
    k_stage1<<<BB, 128, 0, stream>>>(tgt, fmean, idx, We1, be1, Wf1, Wo1, bo1, out_s1, s1b);
    k_gemms<<<71 + BKROWS/32, 256, 0, stream>>>(fbb, s1b, We2, Wo2, be2, bo2,
                                                FBe2b, S1We2, S1Wo2);
    k_stage2<<<BKROWS, 256, 0, stream>>>(idx, FBe2b, S1We2, S1Wo2, Wf2, Wo2, out_s1, out_s2);
}